// Round 1
// baseline (1298.541 us; speedup 1.0000x reference)
//
#include <hip/hip_runtime.h>

// out[b,t,j] = P[b,t,j] + sum_{s=0..t} g[t-s, j] * P[b,s,j]
// B=8, T=4096, NR=256, fp32 in/out.

constexpr int T_  = 4096;
constexpr int NR_ = 256;
constexpr int BB_ = 8;

constexpr int TT = 128;             // t per block
constexpr int SB = 64;              // s per iteration
constexpr int JT = 32;              // channels per block
constexpr int GROWS = TT + SB - 1;  // 191 distinct d = t-s rows per (ti,si)

__global__ __launch_bounds__(256, 4)
void epsi_causal_conv(const float* __restrict__ P,
                      const float* __restrict__ g,
                      float* __restrict__ out)
{
    __shared__ float p_lds[SB][JT];
    __shared__ float g_lds[GROWS + 1][JT];  // row 0 = dummy pad for rr = -1 prefetch

    const int tid  = threadIdx.x;
    const int j    = tid & (JT - 1);
    const int trow = tid >> 5;              // 0..7

    int bx = blockIdx.x;
    const int ti = bx & 31;  bx >>= 5;      // T/TT = 32 (fastest: spreads triangular imbalance)
    const int jt = bx & 7;   bx >>= 3;      // NR/JT = 8
    const int b  = bx;                      // 0..7

    const int t0    = ti * TT;
    const int j0    = jt * JT;
    const int tbase = t0 + trow * 16;

    float acc[16];
#pragma unroll
    for (int k = 0; k < 16; ++k) acc[k] = 0.f;

    const int nsi = 2 * ti + 2;             // s-blocks with s0 <= t0+TT-1
    for (int si = 0; si < nsi; ++si) {
        const int s0   = si * SB;
        const int dmin = t0 - s0 - (SB - 1);

        __syncthreads();  // protect LDS from previous iteration's readers

        // stage P[b, s0..s0+63, j0..j0+31]  (coalesced 128B rows)
#pragma unroll
        for (int it = 0; it < (SB * JT) / 256; ++it) {
            int idx = tid + it * 256;
            int row = idx >> 5;
            int col = idx & (JT - 1);
            p_lds[row][col] = P[((size_t)b * T_ + (s0 + row)) * NR_ + (j0 + col)];
        }
        // stage g rows d = dmin..dmin+190 (zero for d<0 -> masks s>t for free)
        // stored at row index (d - dmin) + 1; row 0 is a dummy pad.
#pragma unroll
        for (int it = 0; it < ((GROWS + 1) * JT) / 256; ++it) {
            int idx = tid + it * 256;
            int row = idx >> 5;             // 0..191
            int col = idx & (JT - 1);
            int d   = dmin + row - 1;
            float v = 0.f;
            if (row >= 1 && d >= 0) v = g[(size_t)d * NR_ + (j0 + col)];
            g_lds[row][col] = v;            // d < T always holds (max d = 4095)
        }
        __syncthreads();

        // 16-entry register ring holding g window rows [16*trow+63-ls .. +15]
        // slot = rr & 15; all slot indices compile-time constant (16x unroll).
        float w[16];
#pragma unroll
        for (int k = 0; k < 16; ++k)
            w[(63 + k) & 15] = g_lds[16 * trow + 63 + k + 1][j];

#pragma unroll 1
        for (int chunk = 0; chunk < SB / 16; ++chunk) {
            const int lsbase = chunk * 16;
#pragma unroll
            for (int u = 0; u < 16; ++u) {
                const int ls = lsbase + u;
                float p = p_lds[ls][j];
#pragma unroll
                for (int k = 0; k < 16; ++k)
                    acc[k] = fmaf(w[(63 - u + k) & 15], p, acc[k]);
                // prefetch next window row rr = 16*trow + 62 - ls (LDS idx rr+1)
                w[(62 - u) & 15] = g_lds[16 * trow + 63 - ls][j];
            }
        }
    }

#pragma unroll
    for (int k = 0; k < 16; ++k) {
        const int t = tbase + k;
        const size_t o = ((size_t)b * T_ + t) * NR_ + (j0 + j);
        out[o] = P[o] + acc[k];
    }
}

extern "C" void kernel_launch(void* const* d_in, const int* in_sizes, int n_in,
                              void* d_out, int out_size, void* d_ws, size_t ws_size,
                              hipStream_t stream) {
    const float* P = (const float*)d_in[0];
    const float* g = (const float*)d_in[1];
    float* out     = (float*)d_out;
    dim3 grid(BB_ * (NR_ / JT) * (T_ / TT));  // 8 * 8 * 32 = 2048 blocks
    epsi_causal_conv<<<grid, 256, 0, stream>>>(P, g, out);
}

// Round 2
// 296.558 us; speedup vs baseline: 4.3787x; 4.3787x over previous
//
#include <hip/hip_runtime.h>

// out[b,t,j] = P[b,t,j] + sum_{s=0..t} g[t-s, j] * P[b,s,j]
// B=8, T=4096, NR=256, fp32 in/out. MFMA path: per-channel Toeplitz matmul in bf16.

typedef short  short4v  __attribute__((ext_vector_type(4)));
typedef short  short8v  __attribute__((ext_vector_type(8)));
typedef float  float4v  __attribute__((ext_vector_type(4)));

constexpr int T_  = 4096;
constexpr int NR_ = 256;
constexpr int BB_ = 8;
constexpr int YSZ = 4288;   // padded flipped-g table length per (copy, j); covers x in [0, 4254]
constexpr size_t GR4_ELEMS = 4ull * NR_ * YSZ;          // 4,390,912 ushort
constexpr size_t PT_ELEMS  = (size_t)BB_ * NR_ * T_;    // 8,388,608 ushort
constexpr size_t WS_NEED   = (GR4_ELEMS + PT_ELEMS + 128) * 2;

__device__ inline unsigned short f2bf(float f) {
    unsigned u = __builtin_bit_cast(unsigned, f);
    unsigned r = (u + 0x7fffu + ((u >> 16) & 1u)) >> 16;
    return (unsigned short)r;
}

// ---------------- prep 1: gr4[c][j][y] = bf16(g[4095 - y - c][j]) or 0 -------------
// 4 copies shifted by c elements so any 8-consecutive-x window is 8B-aligned in some copy.
__global__ void prep_gr4(const float* __restrict__ g, unsigned short* __restrict__ gr4) {
    int ypair = blockIdx.x * 256 + threadIdx.x;
    int y = ypair * 2;
    if (y >= YSZ) return;
    int j = blockIdx.y, c = blockIdx.z;
    int d0 = 4095 - y - c, d1 = d0 - 1;
    float v0 = (d0 >= 0) ? g[(size_t)d0 * NR_ + j] : 0.f;
    float v1 = (d1 >= 0) ? g[(size_t)d1 * NR_ + j] : 0.f;
    unsigned pack = (unsigned)f2bf(v0) | ((unsigned)f2bf(v1) << 16);
    *(unsigned*)(gr4 + ((size_t)(c * NR_ + j) * YSZ + y)) = pack;
}

// ---------------- prep 2: PT[b][j][s] = bf16(P[b][s][j]) ---------------------------
__global__ void prep_pt(const float* __restrict__ P, unsigned short* __restrict__ PT) {
    __shared__ float tile[64][65];
    int s0 = blockIdx.x * 64, j0 = blockIdx.y * 64, b = blockIdx.z;
    for (int i = threadIdx.x; i < 64 * 64; i += 256) {
        int ss = i >> 6, jj = i & 63;
        tile[ss][jj] = P[((size_t)b * T_ + s0 + ss) * NR_ + j0 + jj];
    }
    __syncthreads();
    for (int i = threadIdx.x; i < 64 * 32; i += 256) {
        int jj = i >> 5, sp = i & 31;
        unsigned pack = (unsigned)f2bf(tile[2 * sp][jj]) |
                        ((unsigned)f2bf(tile[2 * sp + 1][jj]) << 16);
        *(unsigned*)(PT + ((size_t)(b * NR_ + j0 + jj) * T_ + s0 + 2 * sp)) = pack;
    }
}

// ---------------- main MFMA kernel -------------------------------------------------
// A[r,k] = G[t0+16rt+r - s0 - k, j] (Toeplitz), B[k,n] = P[b=n&7, s0+k].
// A-frag lane (m=l&15, kb=l>>4): elems e=0..7 at x = 4095-(t0+16rt+m)+s0+kb*8+e (ascending).
// Rolling reuse: frag(rt, s0+32) == frag(rt-2, s0) -> 2 fresh A loads per 8 MFMAs.

__device__ inline short8v ldA(const unsigned short* grj, int x0) {
    int c = x0 & 3, y0 = x0 - c;
    const unsigned short* p = grj + c * (NR_ * YSZ) + y0;   // 8B-aligned by construction
    short4v lo = *(const short4v*)p;
    short4v hi = *(const short4v*)(p + 4);
    return __builtin_shufflevector(lo, hi, 0, 1, 2, 3, 4, 5, 6, 7);
}

__global__ __launch_bounds__(512, 1)
void epsi_mfma(const float* __restrict__ P, const unsigned short* __restrict__ gr4,
               const unsigned short* __restrict__ PT, float* __restrict__ out) {
    __shared__ float etile[32][8][8];   // [t-in-chunk][b][j-in-group]
    const int tid  = threadIdx.x;
    const int w    = tid >> 6;          // wave 0..7 -> channel j0+w
    const int lane = tid & 63;
    const int m    = lane & 15;         // A row / D col (n)
    const int hi   = lane >> 4;         // 0..3
    const int kb8  = hi * 8;
    const int j    = blockIdx.x * 8 + w;
    const int b    = m & 7;
    const unsigned short* grj = gr4 + (size_t)j * YSZ;
    const unsigned short* ptj = PT + (size_t)(b * NR_ + j) * T_ + kb8;

    for (int phase = 0; phase < 2; ++phase) {
        const int tm = (phase == 0) ? (int)blockIdx.y : 31 - (int)blockIdx.y;
        const int t0 = tm * 128;
        const int nsteps = 4 * (tm + 1);           // multiple of 4
        const int XB = 4095 - t0 - m + kb8;

        float4v acc[8];
#pragma unroll
        for (int rt = 0; rt < 8; ++rt) acc[rt] = (float4v){0.f, 0.f, 0.f, 0.f};

        short8v f[8];
        short8v bfr[2];
#pragma unroll
        for (int rt = 0; rt < 8; ++rt) f[rt] = ldA(grj, XB - 16 * rt);
        bfr[0] = *(const short8v*)(ptj);

#define STEP(U) {                                                                      \
        const int s0 = (sg + (U)) * 32;                                                \
        acc[6] = __builtin_amdgcn_mfma_f32_16x16x32_bf16(f[(6 - 2*(U)) & 7], bfr[(U)&1], acc[6], 0,0,0); \
        acc[7] = __builtin_amdgcn_mfma_f32_16x16x32_bf16(f[(7 - 2*(U)) & 7], bfr[(U)&1], acc[7], 0,0,0); \
        f[(0 - 2*((U)+1)) & 7] = ldA(grj, XB + s0 + 32);                               \
        f[(1 - 2*((U)+1)) & 7] = ldA(grj, XB - 16 + s0 + 32);                          \
        bfr[((U)+1) & 1] = *(const short8v*)(ptj + s0 + 32);                           \
        acc[5] = __builtin_amdgcn_mfma_f32_16x16x32_bf16(f[(5 - 2*(U)) & 7], bfr[(U)&1], acc[5], 0,0,0); \
        acc[4] = __builtin_amdgcn_mfma_f32_16x16x32_bf16(f[(4 - 2*(U)) & 7], bfr[(U)&1], acc[4], 0,0,0); \
        acc[3] = __builtin_amdgcn_mfma_f32_16x16x32_bf16(f[(3 - 2*(U)) & 7], bfr[(U)&1], acc[3], 0,0,0); \
        acc[2] = __builtin_amdgcn_mfma_f32_16x16x32_bf16(f[(2 - 2*(U)) & 7], bfr[(U)&1], acc[2], 0,0,0); \
        acc[1] = __builtin_amdgcn_mfma_f32_16x16x32_bf16(f[(1 - 2*(U)) & 7], bfr[(U)&1], acc[1], 0,0,0); \
        acc[0] = __builtin_amdgcn_mfma_f32_16x16x32_bf16(f[(0 - 2*(U)) & 7], bfr[(U)&1], acc[0], 0,0,0); \
        }

        for (int sg = 0; sg < nsteps; sg += 4) {
            STEP(0) STEP(1) STEP(2) STEP(3)
        }
#undef STEP

        // Epilogue: LDS transpose so stores are 16B-contiguous over the 8-channel group.
#pragma unroll 1
        for (int tch = 0; tch < 4; ++tch) {
            __syncthreads();
            if (m < 8) {
#pragma unroll
                for (int rr = 0; rr < 2; ++rr) {
#pragma unroll
                    for (int q = 0; q < 4; ++q)
                        etile[rr * 16 + hi * 4 + q][b][w] = acc[tch * 2 + rr][q];
                }
            }
            __syncthreads();
            {
                int jq = tid & 1, bb = (tid >> 1) & 7, tl = tid >> 4;   // 0..31
                int t = t0 + tch * 32 + tl;
                size_t row = ((size_t)bb * T_ + t) * NR_ + blockIdx.x * 8 + jq * 4;
                float4v pv = *(const float4v*)(P + row);
                float4v av;
                av[0] = etile[tl][bb][jq * 4 + 0];
                av[1] = etile[tl][bb][jq * 4 + 1];
                av[2] = etile[tl][bb][jq * 4 + 2];
                av[3] = etile[tl][bb][jq * 4 + 3];
                *(float4v*)(out + row) = pv + av;
            }
        }
    }
}

// ---------------- fallback (round-1 FMA kernel, used only if ws too small) ---------
constexpr int TT = 128, SB = 64, JT = 32, GROWS = TT + SB - 1;

__global__ __launch_bounds__(256, 4)
void epsi_causal_conv(const float* __restrict__ P, const float* __restrict__ g,
                      float* __restrict__ out) {
    __shared__ float p_lds[SB][JT];
    __shared__ float g_lds[GROWS + 1][JT];
    const int tid = threadIdx.x, j = tid & (JT - 1), trow = tid >> 5;
    int bx = blockIdx.x;
    const int ti = bx & 31; bx >>= 5;
    const int jt = bx & 7;  bx >>= 3;
    const int b = bx;
    const int t0 = ti * TT, j0 = jt * JT, tbase = t0 + trow * 16;
    float acc[16];
#pragma unroll
    for (int k = 0; k < 16; ++k) acc[k] = 0.f;
    const int nsi = 2 * ti + 2;
    for (int si = 0; si < nsi; ++si) {
        const int s0 = si * SB, dmin = t0 - s0 - (SB - 1);
        __syncthreads();
#pragma unroll
        for (int it = 0; it < (SB * JT) / 256; ++it) {
            int idx = tid + it * 256, row = idx >> 5, col = idx & (JT - 1);
            p_lds[row][col] = P[((size_t)b * T_ + (s0 + row)) * NR_ + (j0 + col)];
        }
#pragma unroll
        for (int it = 0; it < ((GROWS + 1) * JT) / 256; ++it) {
            int idx = tid + it * 256, row = idx >> 5, col = idx & (JT - 1);
            int d = dmin + row - 1;
            float v = 0.f;
            if (row >= 1 && d >= 0) v = g[(size_t)d * NR_ + (j0 + col)];
            g_lds[row][col] = v;
        }
        __syncthreads();
        float wreg[16];
#pragma unroll
        for (int k = 0; k < 16; ++k) wreg[(63 + k) & 15] = g_lds[16 * trow + 63 + k + 1][j];
#pragma unroll 1
        for (int chunk = 0; chunk < SB / 16; ++chunk) {
            const int lsbase = chunk * 16;
#pragma unroll
            for (int u = 0; u < 16; ++u) {
                const int ls = lsbase + u;
                float p = p_lds[ls][j];
#pragma unroll
                for (int k = 0; k < 16; ++k)
                    acc[k] = fmaf(wreg[(63 - u + k) & 15], p, acc[k]);
                wreg[(62 - u) & 15] = g_lds[16 * trow + 63 - ls][j];
            }
        }
    }
#pragma unroll
    for (int k = 0; k < 16; ++k) {
        const size_t o = ((size_t)b * T_ + (tbase + k)) * NR_ + (j0 + j);
        out[o] = P[o] + acc[k];
    }
}

extern "C" void kernel_launch(void* const* d_in, const int* in_sizes, int n_in,
                              void* d_out, int out_size, void* d_ws, size_t ws_size,
                              hipStream_t stream) {
    const float* P = (const float*)d_in[0];
    const float* g = (const float*)d_in[1];
    float* out     = (float*)d_out;

    if (ws_size < WS_NEED) {   // defensive fallback
        epsi_causal_conv<<<dim3(BB_ * (NR_ / JT) * (T_ / TT)), 256, 0, stream>>>(P, g, out);
        return;
    }
    unsigned short* gr4 = (unsigned short*)d_ws;
    unsigned short* PT  = gr4 + GR4_ELEMS;

    prep_gr4<<<dim3(9, 256, 4), 256, 0, stream>>>(g, gr4);
    prep_pt <<<dim3(T_ / 64, NR_ / 64, BB_), 256, 0, stream>>>(P, PT);
    epsi_mfma<<<dim3(32, 16), 512, 0, stream>>>(P, gr4, PT, out);
}

// Round 3
// 285.916 us; speedup vs baseline: 4.5417x; 1.0372x over previous
//
#include <hip/hip_runtime.h>

// out[b,t,j] = P[b,t,j] + sum_{s=0..t} g[t-s, j] * P[b,s,j]
// B=8, T=4096, NR=256, fp32 in/out. MFMA path: per-channel Toeplitz matmul in bf16.

typedef short  short4v  __attribute__((ext_vector_type(4)));
typedef short  short8v  __attribute__((ext_vector_type(8)));
typedef float  float4v  __attribute__((ext_vector_type(4)));

constexpr int T_  = 4096;
constexpr int NR_ = 256;
constexpr int BB_ = 8;
constexpr int YSZ = 4288;   // padded flipped-g table length per (copy, j)
constexpr size_t GR4_ELEMS = 4ull * NR_ * YSZ;
constexpr size_t PT_ELEMS  = (size_t)BB_ * NR_ * T_ + 256;  // +256: B depth-3 prefetch overshoot
constexpr size_t WS_NEED   = (GR4_ELEMS + PT_ELEMS + 128) * 2;

__device__ inline unsigned short f2bf(float f) {
    unsigned u = __builtin_bit_cast(unsigned, f);
    unsigned r = (u + 0x7fffu + ((u >> 16) & 1u)) >> 16;
    return (unsigned short)r;
}

// ---------------- prep 1 v2: gr4[c][j][y] = bf16(g[4095 - y - c][j]) ---------------
// Coalesced: 64x64 LDS-transposed tiles. Pad regions (y > 4095-c) pre-zeroed by memset.
__global__ __launch_bounds__(256)
void prep_gr4(const float* __restrict__ g, unsigned short* __restrict__ gr4) {
    __shared__ float tile[64][65];
    const int d0 = blockIdx.x * 64, j0 = blockIdx.y * 64;
#pragma unroll
    for (int it = 0; it < 16; ++it) {
        int idx = it * 256 + threadIdx.x;
        int dd = idx >> 6, jj = idx & 63;
        tile[dd][jj] = g[(size_t)(d0 + dd) * NR_ + (j0 + jj)];
    }
    __syncthreads();
#pragma unroll
    for (int c = 0; c < 4; ++c) {
#pragma unroll
        for (int it = 0; it < 16; ++it) {
            int idx = it * 256 + threadIdx.x;
            int jj = idx >> 6, yy = idx & 63;
            int y = 4032 - c - d0 + yy;            // element for d = d0 + 63 - yy
            if (y >= 0)
                gr4[((size_t)(c * NR_ + j0 + jj)) * YSZ + y] = f2bf(tile[63 - yy][jj]);
        }
    }
}

// ---------------- prep 2: PT[b][j][s] = bf16(P[b][s][j]) ---------------------------
__global__ void prep_pt(const float* __restrict__ P, unsigned short* __restrict__ PT) {
    __shared__ float tile[64][65];
    int s0 = blockIdx.x * 64, j0 = blockIdx.y * 64, b = blockIdx.z;
    for (int i = threadIdx.x; i < 64 * 64; i += 256) {
        int ss = i >> 6, jj = i & 63;
        tile[ss][jj] = P[((size_t)b * T_ + s0 + ss) * NR_ + j0 + jj];
    }
    __syncthreads();
    for (int i = threadIdx.x; i < 64 * 32; i += 256) {
        int jj = i >> 5, sp = i & 31;
        unsigned pack = (unsigned)f2bf(tile[2 * sp][jj]) |
                        ((unsigned)f2bf(tile[2 * sp + 1][jj]) << 16);
        *(unsigned*)(PT + ((size_t)(b * NR_ + j0 + jj) * T_ + s0 + 2 * sp)) = pack;
    }
}

// ---------------- main MFMA kernel -------------------------------------------------
// A[r,k] = G[t0+16rt+r - s0 - k, j] (Toeplitz), B[k,n] = P[b=n&7, s0+k].
// A ring-8, depth-1 (fresh frags consumed LAST next step: ~12-MFMA distance -> L2-covered).
// B ring-4, depth-3 (3-step distance -> L3-covered).  Rolling A reuse: 2 fresh / 8 MFMAs.

__device__ inline short8v ldA(const unsigned short* grj, int x0) {
    int c = x0 & 3, y0 = x0 - c;
    const unsigned short* p = grj + c * (NR_ * YSZ) + y0;   // 8B-aligned by construction
    short4v lo = *(const short4v*)p;
    short4v hi = *(const short4v*)(p + 4);
    return __builtin_shufflevector(lo, hi, 0, 1, 2, 3, 4, 5, 6, 7);
}

__global__ __launch_bounds__(512, 1)
void epsi_mfma(const float* __restrict__ P, const unsigned short* __restrict__ gr4,
               const unsigned short* __restrict__ PT, float* __restrict__ out) {
    __shared__ float etile[32][8][8];   // [t-in-chunk][b][j-in-group]
    const int tid  = threadIdx.x;
    const int w    = tid >> 6;          // wave 0..7 -> channel j0+w
    const int lane = tid & 63;
    const int m    = lane & 15;         // A row / D col (n)
    const int hi   = lane >> 4;         // 0..3
    const int kb8  = hi * 8;
    const int j    = blockIdx.x * 8 + w;
    const int b    = m & 7;
    const unsigned short* grj = gr4 + (size_t)j * YSZ;
    const unsigned short* ptj = PT + (size_t)(b * NR_ + j) * T_ + kb8;

    for (int phase = 0; phase < 2; ++phase) {
        const int tm = (phase == 0) ? (int)blockIdx.y : 31 - (int)blockIdx.y;
        const int t0 = tm * 128;
        const int nsteps = 4 * (tm + 1);           // multiple of 4
        const int XB = 4095 - t0 - m + kb8;

        float4v acc[8];
#pragma unroll
        for (int rt = 0; rt < 8; ++rt) acc[rt] = (float4v){0.f, 0.f, 0.f, 0.f};

        short8v f[8];
        short8v bfr[4];
#pragma unroll
        for (int rt = 0; rt < 8; ++rt) f[rt] = ldA(grj, XB - 16 * rt);
        bfr[0] = *(const short8v*)(ptj);
        bfr[1] = *(const short8v*)(ptj + 32);
        bfr[2] = *(const short8v*)(ptj + 64);

#define STEP(U) {                                                                      \
        const int s0 = (sg + (U)) * 32;                                                \
        acc[6] = __builtin_amdgcn_mfma_f32_16x16x32_bf16(f[(6 - 2*(U)) & 7], bfr[(U)&3], acc[6], 0,0,0); \
        acc[7] = __builtin_amdgcn_mfma_f32_16x16x32_bf16(f[(7 - 2*(U)) & 7], bfr[(U)&3], acc[7], 0,0,0); \
        f[(0 - 2*((U)+1)) & 7] = ldA(grj, XB + s0 + 32);                               \
        f[(1 - 2*((U)+1)) & 7] = ldA(grj, XB - 16 + s0 + 32);                          \
        bfr[((U)+3) & 3] = *(const short8v*)(ptj + s0 + 96);                           \
        acc[5] = __builtin_amdgcn_mfma_f32_16x16x32_bf16(f[(5 - 2*(U)) & 7], bfr[(U)&3], acc[5], 0,0,0); \
        acc[4] = __builtin_amdgcn_mfma_f32_16x16x32_bf16(f[(4 - 2*(U)) & 7], bfr[(U)&3], acc[4], 0,0,0); \
        acc[3] = __builtin_amdgcn_mfma_f32_16x16x32_bf16(f[(3 - 2*(U)) & 7], bfr[(U)&3], acc[3], 0,0,0); \
        acc[2] = __builtin_amdgcn_mfma_f32_16x16x32_bf16(f[(2 - 2*(U)) & 7], bfr[(U)&3], acc[2], 0,0,0); \
        acc[1] = __builtin_amdgcn_mfma_f32_16x16x32_bf16(f[(1 - 2*(U)) & 7], bfr[(U)&3], acc[1], 0,0,0); \
        acc[0] = __builtin_amdgcn_mfma_f32_16x16x32_bf16(f[(0 - 2*(U)) & 7], bfr[(U)&3], acc[0], 0,0,0); \
        }

        for (int sg = 0; sg < nsteps; sg += 4) {
            STEP(0) STEP(1) STEP(2) STEP(3)
        }
#undef STEP

        // Epilogue: LDS transpose so stores are 16B-contiguous over the 8-channel group.
#pragma unroll 1
        for (int tch = 0; tch < 4; ++tch) {
            __syncthreads();
            if (m < 8) {
#pragma unroll
                for (int rr = 0; rr < 2; ++rr) {
#pragma unroll
                    for (int q = 0; q < 4; ++q)
                        etile[rr * 16 + hi * 4 + q][b][w] = acc[tch * 2 + rr][q];
                }
            }
            __syncthreads();
            {
                int jq = tid & 1, bb = (tid >> 1) & 7, tl = tid >> 4;   // 0..31
                int t = t0 + tch * 32 + tl;
                size_t row = ((size_t)bb * T_ + t) * NR_ + blockIdx.x * 8 + jq * 4;
                float4v pv = *(const float4v*)(P + row);
                float4v av;
                av[0] = etile[tl][bb][jq * 4 + 0];
                av[1] = etile[tl][bb][jq * 4 + 1];
                av[2] = etile[tl][bb][jq * 4 + 2];
                av[3] = etile[tl][bb][jq * 4 + 3];
                *(float4v*)(out + row) = pv + av;
            }
        }
    }
}

// ---------------- fallback (round-1 FMA kernel, used only if ws too small) ---------
constexpr int TT = 128, SB = 64, JT = 32, GROWS = TT + SB - 1;

__global__ __launch_bounds__(256, 4)
void epsi_causal_conv(const float* __restrict__ P, const float* __restrict__ g,
                      float* __restrict__ out) {
    __shared__ float p_lds[SB][JT];
    __shared__ float g_lds[GROWS + 1][JT];
    const int tid = threadIdx.x, j = tid & (JT - 1), trow = tid >> 5;
    int bx = blockIdx.x;
    const int ti = bx & 31; bx >>= 5;
    const int jt = bx & 7;  bx >>= 3;
    const int b = bx;
    const int t0 = ti * TT, j0 = jt * JT, tbase = t0 + trow * 16;
    float acc[16];
#pragma unroll
    for (int k = 0; k < 16; ++k) acc[k] = 0.f;
    const int nsi = 2 * ti + 2;
    for (int si = 0; si < nsi; ++si) {
        const int s0 = si * SB, dmin = t0 - s0 - (SB - 1);
        __syncthreads();
#pragma unroll
        for (int it = 0; it < (SB * JT) / 256; ++it) {
            int idx = tid + it * 256, row = idx >> 5, col = idx & (JT - 1);
            p_lds[row][col] = P[((size_t)b * T_ + (s0 + row)) * NR_ + (j0 + col)];
        }
#pragma unroll
        for (int it = 0; it < ((GROWS + 1) * JT) / 256; ++it) {
            int idx = tid + it * 256, row = idx >> 5, col = idx & (JT - 1);
            int d = dmin + row - 1;
            float v = 0.f;
            if (row >= 1 && d >= 0) v = g[(size_t)d * NR_ + (j0 + col)];
            g_lds[row][col] = v;
        }
        __syncthreads();
        float wreg[16];
#pragma unroll
        for (int k = 0; k < 16; ++k) wreg[(63 + k) & 15] = g_lds[16 * trow + 63 + k + 1][j];
#pragma unroll 1
        for (int chunk = 0; chunk < SB / 16; ++chunk) {
            const int lsbase = chunk * 16;
#pragma unroll
            for (int u = 0; u < 16; ++u) {
                const int ls = lsbase + u;
                float p = p_lds[ls][j];
#pragma unroll
                for (int k = 0; k < 16; ++k)
                    acc[k] = fmaf(wreg[(63 - u + k) & 15], p, acc[k]);
                wreg[(62 - u) & 15] = g_lds[16 * trow + 63 - ls][j];
            }
        }
    }
#pragma unroll
    for (int k = 0; k < 16; ++k) {
        const size_t o = ((size_t)b * T_ + (tbase + k)) * NR_ + (j0 + j);
        out[o] = P[o] + acc[k];
    }
}

extern "C" void kernel_launch(void* const* d_in, const int* in_sizes, int n_in,
                              void* d_out, int out_size, void* d_ws, size_t ws_size,
                              hipStream_t stream) {
    const float* P = (const float*)d_in[0];
    const float* g = (const float*)d_in[1];
    float* out     = (float*)d_out;

    if (ws_size < WS_NEED) {   // defensive fallback
        epsi_causal_conv<<<dim3(BB_ * (NR_ / JT) * (T_ / TT)), 256, 0, stream>>>(P, g, out);
        return;
    }
    unsigned short* gr4 = (unsigned short*)d_ws;
    unsigned short* PT  = gr4 + GR4_ELEMS;

    hipMemsetAsync(gr4, 0, GR4_ELEMS * sizeof(unsigned short), stream);
    prep_gr4<<<dim3(T_ / 64, NR_ / 64), 256, 0, stream>>>(g, gr4);
    prep_pt <<<dim3(T_ / 64, NR_ / 64, BB_), 256, 0, stream>>>(P, PT);
    epsi_mfma<<<dim3(32, 16), 512, 0, stream>>>(P, gr4, PT, out);
}

// Round 5
// 189.843 us; speedup vs baseline: 6.8401x; 1.5061x over previous
//
#include <hip/hip_runtime.h>

// out[b,t,j] = P[b,t,j] + sum_{s=0..t} g[t-s, j] * P[b,s,j]
// B=8, T=4096, NR=256, fp32 in/out. MFMA Toeplitz matmul, LDS-pipelined (2-phase schedule).

typedef short  short4v  __attribute__((ext_vector_type(4)));
typedef short  short8v  __attribute__((ext_vector_type(8)));
typedef float  float4v  __attribute__((ext_vector_type(4)));

constexpr int T_  = 4096;
constexpr int NR_ = 256;
constexpr int BB_ = 8;
constexpr int YSZ = 4352;   // flipped-g table length per (copy,j); strip reads reach 4335
constexpr size_t GR4_ELEMS = 4ull * NR_ * YSZ;
constexpr size_t PT_ELEMS  = (size_t)BB_ * NR_ * T_ + 256;
constexpr size_t WS_NEED   = (GR4_ELEMS + PT_ELEMS + 128) * 2;

__device__ inline unsigned short f2bf(float f) {
    unsigned u = __builtin_bit_cast(unsigned, f);
    unsigned r = (u + 0x7fffu + ((u >> 16) & 1u)) >> 16;
    return (unsigned short)r;
}

__device__ __forceinline__ void gload16(const unsigned short* src, unsigned short* dst) {
    __builtin_amdgcn_global_load_lds(
        (const __attribute__((address_space(1))) unsigned int*)src,
        (__attribute__((address_space(3))) unsigned int*)dst, 16, 0, 0);
}

// ---------------- prep 1: gr4[c][j][y] = bf16(g[4095 - y - c][j]) (pads memset-0) ---
__global__ __launch_bounds__(256)
void prep_gr4(const float* __restrict__ g, unsigned short* __restrict__ gr4) {
    __shared__ float tile[64][65];
    const int d0 = blockIdx.x * 64, j0 = blockIdx.y * 64;
#pragma unroll
    for (int it = 0; it < 16; ++it) {
        int idx = it * 256 + threadIdx.x;
        int dd = idx >> 6, jj = idx & 63;
        tile[dd][jj] = g[(size_t)(d0 + dd) * NR_ + (j0 + jj)];
    }
    __syncthreads();
#pragma unroll
    for (int c = 0; c < 4; ++c) {
#pragma unroll
        for (int it = 0; it < 16; ++it) {
            int idx = it * 256 + threadIdx.x;
            int jj = idx >> 6, yy = idx & 63;
            int y = 4032 - c - d0 + yy;            // element for d = d0 + 63 - yy
            if (y >= 0)
                gr4[((size_t)(c * NR_ + j0 + jj)) * YSZ + y] = f2bf(tile[63 - yy][jj]);
        }
    }
}

// ---------------- prep 2: PT[b][j][s] = bf16(P[b][s][j]) ---------------------------
__global__ void prep_pt(const float* __restrict__ P, unsigned short* __restrict__ PT) {
    __shared__ float tile[64][65];
    int s0 = blockIdx.x * 64, j0 = blockIdx.y * 64, b = blockIdx.z;
    for (int i = threadIdx.x; i < 64 * 64; i += 256) {
        int ss = i >> 6, jj = i & 63;
        tile[ss][jj] = P[((size_t)b * T_ + s0 + ss) * NR_ + j0 + jj];
    }
    __syncthreads();
    for (int i = threadIdx.x; i < 64 * 32; i += 256) {
        int jj = i >> 5, sp = i & 31;
        unsigned pack = (unsigned)f2bf(tile[2 * sp][jj]) |
                        ((unsigned)f2bf(tile[2 * sp + 1][jj]) << 16);
        *(unsigned*)(PT + ((size_t)(b * NR_ + j0 + jj) * T_ + s0 + 2 * sp)) = pack;
    }
}

// ---------------- main MFMA kernel -------------------------------------------------
// Per 4-step group (128 s): stage next group's A-strip (32 rows x 256 el) and B-tile
// (8j x 8b x 128s, XOR-swizzled) into LDS dbuf via global_load_lds; compute current
// group from LDS. One vmcnt(0)+lgkmcnt(0)+s_barrier per group (T3 minimum recipe).

__device__ inline short8v ldA(const unsigned short* grj, int x0) {
    int c = x0 & 3, y0 = x0 - c;
    const unsigned short* p = grj + c * (NR_ * YSZ) + y0;
    short4v lo = *(const short4v*)p;
    short4v hi = *(const short4v*)(p + 4);
    return __builtin_shufflevector(lo, hi, 0, 1, 2, 3, 4, 5, 6, 7);
}

#define MF(A, B, C) __builtin_amdgcn_mfma_f32_16x16x32_bf16((A), (B), (C), 0, 0, 0)

__global__ __launch_bounds__(512, 4)
void epsi_mfma(const float* __restrict__ P, const unsigned short* __restrict__ gr4,
               const unsigned short* __restrict__ PT, float* __restrict__ out) {
    __shared__ unsigned short Ab[2][8192];    // [buf][ (c*8+j)*256 + rel ]
    __shared__ unsigned short Bbf[2][8192];   // [buf][ j*1024 + s8*64 + (b^(s8&7))*8 + e ]
    __shared__ float etile[32][8][8];

    const int tid  = threadIdx.x;
    const int w    = tid >> 6;
    const int lane = tid & 63;
    const int m    = lane & 15;
    const int hi   = lane >> 4;               // = kb
    const int kb8  = hi * 8;
    const int j0g  = blockIdx.x * 8;
    const int j    = j0g + w;
    const int b    = m & 7;
    const unsigned short* grj = gr4 + (size_t)j * YSZ;

    // B-frag read offsets: addr(U) = bofs[U&1] + U*256
    const int bofs0 = w * 1024 + hi * 64 + ((b ^ hi) << 3);
    const int bofs1 = w * 1024 + hi * 64 + ((b ^ (hi + 4)) << 3);
    // A-frag read base: fresh1(U) at abase + 32U + 32, fresh2 at -16
    const int arel  = 15 - m + kb8;
    const int cA    = arel & 3;
    const int abase = ((cA << 3) + w) * 256 + (arel - cA);

    // staging sources (slot q0 = w*128+lane, q1 = +64); dests are lane-linear
    const int slot0 = w * 128 + lane, slot1 = slot0 + 64;
    const unsigned short *bsrc0, *bsrc1, *asrc0, *asrc1;
    {
        int jl0 = slot0 >> 7, s80 = (slot0 >> 3) & 15, bp0 = slot0 & 7;
        int jl1 = slot1 >> 7, s81 = (slot1 >> 3) & 15, bp1 = slot1 & 7;
        bsrc0 = PT + ((size_t)((bp0 ^ (s80 & 7)) * NR_ + j0g + jl0) * T_ + s80 * 8);
        bsrc1 = PT + ((size_t)((bp1 ^ (s81 & 7)) * NR_ + j0g + jl1) * T_ + s81 * 8);
        int r0 = slot0 >> 5, o0 = (slot0 & 31) * 8;
        int r1 = slot1 >> 5, o1 = (slot1 & 31) * 8;
        asrc0 = gr4 + ((size_t)((r0 >> 3) * NR_ + j0g + (r0 & 7)) * YSZ + o0);
        asrc1 = gr4 + ((size_t)((r1 >> 3) * NR_ + j0g + (r1 & 7)) * YSZ + o1);
    }

#define STAGE(BUFI, G, T0) {                                          \
        int s0g_ = (G) << 7;                                          \
        int xlo_ = 4080 - (T0) + ((G) << 7);                          \
        gload16(bsrc0 + s0g_, &Bbf[BUFI][w * 1024]);                  \
        gload16(bsrc1 + s0g_, &Bbf[BUFI][w * 1024 + 512]);            \
        gload16(asrc0 + xlo_, &Ab[BUFI][w * 1024]);                   \
        gload16(asrc1 + xlo_, &Ab[BUFI][w * 1024 + 512]);             \
    }

#define STEPG(U) {                                                    \
        short8v bq = *(const short8v*)(Bc + (((U)&1) ? bofs1 : bofs0) + (U) * 256); \
        acc[6] = MF(f[(6 - 2*(U)) & 7], bq, acc[6]);                  \
        acc[7] = MF(f[(7 - 2*(U)) & 7], bq, acc[7]);                  \
        { const int a1 = abase + 32 * (U) + 32;                       \
          short4v lo1 = *(const short4v*)(Ac + a1);                   \
          short4v hi1 = *(const short4v*)(Ac + a1 + 4);               \
          short4v lo2 = *(const short4v*)(Ac + a1 - 16);              \
          short4v hi2 = *(const short4v*)(Ac + a1 - 12);              \
          f[(6 - 2*(U)) & 7] = __builtin_shufflevector(lo1, hi1, 0,1,2,3,4,5,6,7); \
          f[(7 - 2*(U)) & 7] = __builtin_shufflevector(lo2, hi2, 0,1,2,3,4,5,6,7); \
        }                                                             \
        acc[5] = MF(f[(5 - 2*(U)) & 7], bq, acc[5]);                  \
        acc[4] = MF(f[(4 - 2*(U)) & 7], bq, acc[4]);                  \
        acc[3] = MF(f[(3 - 2*(U)) & 7], bq, acc[3]);                  \
        acc[2] = MF(f[(2 - 2*(U)) & 7], bq, acc[2]);                  \
        acc[1] = MF(f[(1 - 2*(U)) & 7], bq, acc[1]);                  \
        acc[0] = MF(f[(0 - 2*(U)) & 7], bq, acc[0]);                  \
    }

    for (int phase = 0; phase < 2; ++phase) {
        const int tm = (phase == 0) ? (int)blockIdx.y : 31 - (int)blockIdx.y;
        const int t0 = tm * 128;
        const int XB = 4095 - t0 - m + kb8;

        float4v acc[8];
#pragma unroll
        for (int rt = 0; rt < 8; ++rt) acc[rt] = (float4v){0.f, 0.f, 0.f, 0.f};

        short8v f[8];
#pragma unroll
        for (int rt = 0; rt < 8; ++rt) f[rt] = ldA(grj, XB - 16 * rt);  // ring init (global)

        STAGE(0, 0, t0);
        asm volatile("s_waitcnt vmcnt(0) lgkmcnt(0)" ::: "memory");
        __builtin_amdgcn_s_barrier();
        __builtin_amdgcn_sched_barrier(0);

#pragma unroll 1
        for (int g = 0; g <= tm; ++g) {
            if (g < tm) STAGE((g + 1) & 1, g + 1, t0);   // issue-early, drain-late
            const unsigned short* Ac = Ab[g & 1];
            const unsigned short* Bc = Bbf[g & 1];
            STEPG(0) STEPG(1) STEPG(2) STEPG(3)
            asm volatile("s_waitcnt vmcnt(0) lgkmcnt(0)" ::: "memory");
            __builtin_amdgcn_s_barrier();
            __builtin_amdgcn_sched_barrier(0);
        }

        // Epilogue (unchanged from verified round-2 kernel)
#pragma unroll 1
        for (int tch = 0; tch < 4; ++tch) {
            __syncthreads();
            if (m < 8) {
#pragma unroll
                for (int rr = 0; rr < 2; ++rr) {
#pragma unroll
                    for (int q = 0; q < 4; ++q)
                        etile[rr * 16 + hi * 4 + q][b][w] = acc[tch * 2 + rr][q];
                }
            }
            __syncthreads();
            {
                int jq = tid & 1, bb = (tid >> 1) & 7, tl = tid >> 4;
                int t = t0 + tch * 32 + tl;
                size_t row = ((size_t)bb * T_ + t) * NR_ + j0g + jq * 4;
                float4v pv = *(const float4v*)(P + row);
                float4v av;
                av[0] = etile[tl][bb][jq * 4 + 0];
                av[1] = etile[tl][bb][jq * 4 + 1];
                av[2] = etile[tl][bb][jq * 4 + 2];
                av[3] = etile[tl][bb][jq * 4 + 3];
                *(float4v*)(out + row) = pv + av;
            }
        }
    }
#undef STAGE
#undef STEPG
}

// ---------------- fallback (round-1 FMA kernel) ------------------------------------
constexpr int TT = 128, SB = 64, JT = 32, GROWS = TT + SB - 1;

__global__ __launch_bounds__(256, 4)
void epsi_causal_conv(const float* __restrict__ P, const float* __restrict__ g,
                      float* __restrict__ out) {
    __shared__ float p_lds[SB][JT];
    __shared__ float g_lds[GROWS + 1][JT];
    const int tid = threadIdx.x, j = tid & (JT - 1), trow = tid >> 5;
    int bx = blockIdx.x;
    const int ti = bx & 31; bx >>= 5;
    const int jt = bx & 7;  bx >>= 3;
    const int b = bx;
    const int t0 = ti * TT, j0 = jt * JT, tbase = t0 + trow * 16;
    float acc[16];
#pragma unroll
    for (int k = 0; k < 16; ++k) acc[k] = 0.f;
    const int nsi = 2 * ti + 2;
    for (int si = 0; si < nsi; ++si) {
        const int s0 = si * SB, dmin = t0 - s0 - (SB - 1);
        __syncthreads();
#pragma unroll
        for (int it = 0; it < (SB * JT) / 256; ++it) {
            int idx = tid + it * 256, row = idx >> 5, col = idx & (JT - 1);
            p_lds[row][col] = P[((size_t)b * T_ + (s0 + row)) * NR_ + (j0 + col)];
        }
#pragma unroll
        for (int it = 0; it < ((GROWS + 1) * JT) / 256; ++it) {
            int idx = tid + it * 256, row = idx >> 5, col = idx & (JT - 1);
            int d = dmin + row - 1;
            float v = 0.f;
            if (row >= 1 && d >= 0) v = g[(size_t)d * NR_ + (j0 + col)];
            g_lds[row][col] = v;
        }
        __syncthreads();
        float wreg[16];
#pragma unroll
        for (int k = 0; k < 16; ++k) wreg[(63 + k) & 15] = g_lds[16 * trow + 63 + k + 1][j];
#pragma unroll 1
        for (int chunk = 0; chunk < SB / 16; ++chunk) {
            const int lsbase = chunk * 16;
#pragma unroll
            for (int u = 0; u < 16; ++u) {
                const int ls = lsbase + u;
                float p = p_lds[ls][j];
#pragma unroll
                for (int k = 0; k < 16; ++k)
                    acc[k] = fmaf(wreg[(63 - u + k) & 15], p, acc[k]);
                wreg[(62 - u) & 15] = g_lds[16 * trow + 63 - ls][j];
            }
        }
    }
#pragma unroll
    for (int k = 0; k < 16; ++k) {
        const size_t o = ((size_t)b * T_ + (tbase + k)) * NR_ + (j0 + j);
        out[o] = P[o] + acc[k];
    }
}

extern "C" void kernel_launch(void* const* d_in, const int* in_sizes, int n_in,
                              void* d_out, int out_size, void* d_ws, size_t ws_size,
                              hipStream_t stream) {
    const float* P = (const float*)d_in[0];
    const float* g = (const float*)d_in[1];
    float* out     = (float*)d_out;

    if (ws_size < WS_NEED) {   // defensive fallback
        epsi_causal_conv<<<dim3(BB_ * (NR_ / JT) * (T_ / TT)), 256, 0, stream>>>(P, g, out);
        return;
    }
    unsigned short* gr4 = (unsigned short*)d_ws;
    unsigned short* PT  = gr4 + GR4_ELEMS;

    hipMemsetAsync(gr4, 0, GR4_ELEMS * sizeof(unsigned short), stream);
    prep_gr4<<<dim3(T_ / 64, NR_ / 64), 256, 0, stream>>>(g, gr4);
    prep_pt <<<dim3(T_ / 64, NR_ / 64, BB_), 256, 0, stream>>>(P, PT);
    epsi_mfma<<<dim3(32, 16), 512, 0, stream>>>(P, gr4, PT, out);
}